// Round 4
// baseline (60.051 us; speedup 1.0000x reference)
//
#include <hip/hip_runtime.h>
#include <hip/hip_bf16.h>
#include <math.h>

#define EPS 1e-5f
#define QSCALE 0.36067376022224085f   // 0.25 * log2(e)

typedef __attribute__((ext_vector_type(8))) short bf16x8;
typedef __attribute__((ext_vector_type(8))) unsigned short ushort8;
typedef __attribute__((ext_vector_type(16))) float f32x16;

__device__ inline unsigned short f2bf(float x) {
    __hip_bfloat16 b = __float2bfloat16(x);
    return *reinterpret_cast<unsigned short*>(&b);
}
__device__ inline float bf2f(unsigned short u) {
    unsigned int v = ((unsigned int)u) << 16;
    return __uint_as_float(v);
}

// ---------------------------------------------------------------------------
// MFMA GEMM + BN.  out[b,o,n] = BN_o( sum_c w[o,c] * src[b,c,n] )
// BM=128, BN=64, K=256 in 2 steps of 128. 4 waves, M-split.
// QKV: src fp32, epilogue -> qt/kt bf16 [bh][n][16] (q pre-scaled QSCALE) +
//      vt bf16 planes [bh*32+c][n].
// PROJ: src bf16 (y), epilogue -> fp32 out.
// ---------------------------------------------------------------------------
template<int CO, bool QKV>
__global__ __launch_bounds__(256)
void gemm_mfma_kernel(const float* __restrict__ srcf, const unsigned short* __restrict__ srcb,
                      const float* __restrict__ w,
                      const float* __restrict__ g, const float* __restrict__ bbias,
                      const float* __restrict__ bmean, const float* __restrict__ bvar,
                      float* __restrict__ out,
                      unsigned short* __restrict__ qt,
                      unsigned short* __restrict__ kt,
                      unsigned short* __restrict__ vt)
{
    const int b  = blockIdx.z;
    const int o0 = blockIdx.y * 128;
    const int n0 = blockIdx.x * 64;

    __shared__ unsigned short As[128][136];  // [o][k]
    __shared__ unsigned short Bs[64][136];   // [n][k]

    const int tid = threadIdx.x;
    const int wid = tid >> 6;
    const int lane = tid & 63;
    const int col = lane & 31;
    const int h2 = lane >> 5;

    f32x16 acc0 = {}, acc1 = {};

    #pragma unroll
    for (int s = 0; s < 2; s++) {
        const int k0 = s * 128;
        __syncthreads();
        // stage A: 128 o x 128 k fp32 -> bf16
        #pragma unroll
        for (int i = 0; i < 16; i++) {
            int flat = tid + i * 256;
            int row = flat >> 5;
            int kq  = flat & 31;
            float4 a4 = *(const float4*)&w[(size_t)(o0 + row) * 256 + k0 + kq * 4];
            unsigned int w0 = f2bf(a4.x) | ((unsigned int)f2bf(a4.y) << 16);
            unsigned int w1 = f2bf(a4.z) | ((unsigned int)f2bf(a4.w) << 16);
            *(uint2*)&As[row][kq * 4] = make_uint2(w0, w1);
        }
        // stage B transposed: src [c][n] -> Bs [n][k=c]
        if (QKV) {
            const float* xb = srcf + (size_t)b * 256 * 1024;
            #pragma unroll
            for (int i = 0; i < 8; i++) {
                int flat = tid + i * 256;
                int c  = flat >> 4;
                int nq = flat & 15;
                float4 b4 = *(const float4*)&xb[(size_t)(k0 + c) * 1024 + n0 + nq * 4];
                Bs[nq * 4 + 0][c] = f2bf(b4.x);
                Bs[nq * 4 + 1][c] = f2bf(b4.y);
                Bs[nq * 4 + 2][c] = f2bf(b4.z);
                Bs[nq * 4 + 3][c] = f2bf(b4.w);
            }
        } else {
            const unsigned short* yb = srcb + (size_t)b * 256 * 1024;
            #pragma unroll
            for (int i = 0; i < 4; i++) {
                int flat = tid + i * 256;
                int c  = flat >> 3;
                int nq = flat & 7;
                ushort8 v8 = *(const ushort8*)&yb[(size_t)(k0 + c) * 1024 + n0 + nq * 8];
                #pragma unroll
                for (int jj = 0; jj < 8; jj++) Bs[nq * 8 + jj][c] = v8[jj];
            }
        }
        __syncthreads();
        #pragma unroll
        for (int ks = 0; ks < 8; ks++) {
            bf16x8 af = *(bf16x8*)&As[wid * 32 + col][ks * 16 + 8 * h2];
            bf16x8 b0 = *(bf16x8*)&Bs[col][ks * 16 + 8 * h2];
            bf16x8 b1 = *(bf16x8*)&Bs[32 + col][ks * 16 + 8 * h2];
            acc0 = __builtin_amdgcn_mfma_f32_32x32x16_bf16(af, b0, acc0, 0, 0, 0);
            acc1 = __builtin_amdgcn_mfma_f32_32x32x16_bf16(af, b1, acc1, 0, 0, 0);
        }
    }

    // epilogue: D row o = o0+wid*32+(r&3)+8*(r>>2)+4*h2, col n = n0+t*32+col
    #pragma unroll
    for (int gq = 0; gq < 4; gq++) {
        const int ob = o0 + wid * 32 + 8 * gq + 4 * h2;
        float4 gg = *(const float4*)&g[ob];
        float4 bb = *(const float4*)&bbias[ob];
        float4 mm = *(const float4*)&bmean[ob];
        float4 vv = *(const float4*)&bvar[ob];
        float sm[4], sa[4];
        sm[0] = gg.x * rsqrtf(vv.x + EPS); sa[0] = bb.x - mm.x * sm[0];
        sm[1] = gg.y * rsqrtf(vv.y + EPS); sa[1] = bb.y - mm.y * sm[1];
        sm[2] = gg.z * rsqrtf(vv.z + EPS); sa[2] = bb.z - mm.z * sm[2];
        sm[3] = gg.w * rsqrtf(vv.w + EPS); sa[3] = bb.w - mm.w * sm[3];

        #pragma unroll
        for (int t = 0; t < 2; t++) {
            const f32x16& ac = t ? acc1 : acc0;
            const int n = n0 + t * 32 + col;
            float val[4];
            #pragma unroll
            for (int j = 0; j < 4; j++) val[j] = ac[4 * gq + j] * sm[j] + sa[j];

            if (!QKV) {
                #pragma unroll
                for (int j = 0; j < 4; j++)
                    out[((size_t)b * CO + ob + j) * 1024 + n] = val[j];
            } else {
                const int h  = blockIdx.y * 2 + (wid >> 1);
                const int bh = b * 8 + h;
                const int rb = 8 * gq + 4 * h2;         // row within 32-row half
                if ((wid & 1) == 0) {
                    // q/k half: rb<16 -> q (scaled to exp2 domain), else k
                    const bool isq = (gq < 2);
                    if (isq) {
                        #pragma unroll
                        for (int j = 0; j < 4; j++) val[j] *= QSCALE;
                    }
                    unsigned int w0 = f2bf(val[0]) | ((unsigned int)f2bf(val[1]) << 16);
                    unsigned int w1 = f2bf(val[2]) | ((unsigned int)f2bf(val[3]) << 16);
                    unsigned short* dst = (isq ? qt : kt)
                        + ((size_t)(bh * 1024 + n) * 16 + (rb & 15));
                    *(uint2*)dst = make_uint2(w0, w1);
                } else {
                    // v half: channel = rb + j, plane layout [bh*32+c][m=n]
                    #pragma unroll
                    for (int j = 0; j < 4; j++)
                        vt[(size_t)(bh * 32 + rb + j) * 1024 + n] = f2bf(val[j]);
                }
            }
        }
    }
}

// ---------------------------------------------------------------------------
// Depthwise 3x3 conv + BN on bf16 v planes -> WRITES pe (fp32).
// ---------------------------------------------------------------------------
__global__ __launch_bounds__(256)
void pe_conv_bn_kernel(const unsigned short* __restrict__ vt, const float* __restrict__ wpe,
                       const float* __restrict__ g, const float* __restrict__ bbias,
                       const float* __restrict__ bmean, const float* __restrict__ bvar,
                       float* __restrict__ pe)
{
    const int bc = blockIdx.x;
    const int b = bc >> 8, ch = bc & 255;
    const unsigned short* vp = vt + (size_t)(b * 256 + ch) * 1024;

    __shared__ float plane[1024];
    const int tid = threadIdx.x;
    {
        ushort4 r4 = *(const ushort4*)&vp[tid * 4];
        float4 f4 = make_float4(bf2f(r4.x), bf2f(r4.y), bf2f(r4.z), bf2f(r4.w));
        *(float4*)&plane[tid * 4] = f4;
    }

    float wk[9];
    #pragma unroll
    for (int i = 0; i < 9; i++) wk[i] = wpe[ch * 9 + i];
    float s  = g[ch] * rsqrtf(bvar[ch] + EPS);
    float sh = bbias[ch] - bmean[ch] * s;
    __syncthreads();

    float* yp = pe + ((size_t)b * 256 + ch) * 1024;
    #pragma unroll
    for (int it = 0; it < 4; it++) {
        int p = tid + it * 256;
        int py = p >> 5, px = p & 31;
        float a = 0.f;
        #pragma unroll
        for (int dy = -1; dy <= 1; dy++) {
            int yy = py + dy;
            if (yy < 0 || yy > 31) continue;
            #pragma unroll
            for (int dx = -1; dx <= 1; dx++) {
                int xx = px + dx;
                if (xx < 0 || xx > 31) continue;
                a += plane[yy * 32 + xx] * wk[(dy + 1) * 3 + (dx + 1)];
            }
        }
        yp[p] = a * s + sh;
    }
}

// ---------------------------------------------------------------------------
// MFMA flash attention, 8 waves = 4 query sub-tiles x 2 key-splits.
// Waves ksplit=0 handle keys 0..511, ksplit=1 keys 512..1023; merged via LDS.
// Softmax in exp2 domain (q pre-scaled). Reads pe (fp32), writes y (bf16) once.
// ---------------------------------------------------------------------------
__global__ __launch_bounds__(512)
void attn_mfma_kernel(const unsigned short* __restrict__ qt,
                      const unsigned short* __restrict__ kt,
                      const unsigned short* __restrict__ vt,
                      const float* __restrict__ pe,
                      unsigned short* __restrict__ y)
{
    const int bh = blockIdx.y;
    const int b = bh >> 3, h = bh & 7;
    const int tid = threadIdx.x;
    const int wid = tid >> 6;
    const int qsub = wid & 3;
    const int ksplit = wid >> 2;
    const int lane = tid & 63;
    const int col = lane & 31;
    const int h2 = lane >> 5;
    const int q0 = blockIdx.x * 128 + qsub * 32;

    __shared__ unsigned short p_lds[8][32][40];
    __shared__ float cmb[4][64][17];
    __shared__ float cmm[4][64];
    __shared__ float cml[4][64];

    const bf16x8 qf = *(const bf16x8*)(qt + ((size_t)bh * 1024 + q0 + col) * 16 + h2 * 8);
    const unsigned short* ktb = kt + (size_t)bh * 1024 * 16;
    const unsigned short* vtb = vt + (size_t)bh * 32 * 1024 + (size_t)col * 1024 + 8 * h2;

    f32x16 acc = {};
    float mrun = -1e30f, lrun = 0.f;

    const int j0 = ksplit * 16;
    bf16x8 kf  = *(const bf16x8*)(ktb + (size_t)(j0 * 32 + col) * 16 + h2 * 8);
    bf16x8 vf0 = *(const bf16x8*)(vtb + j0 * 32);
    bf16x8 vf1 = *(const bf16x8*)(vtb + j0 * 32 + 16);

    for (int j = j0; j < j0 + 16; j++) {
        const f32x16 zero = {};
        f32x16 s = __builtin_amdgcn_mfma_f32_32x32x16_bf16(kf, qf, zero, 0, 0, 0);

        // prefetch next chunk's fragments
        bf16x8 kfn, vf0n, vf1n;
        if (j < j0 + 15) {
            const int m1 = (j + 1) * 32;
            kfn  = *(const bf16x8*)(ktb + (size_t)(m1 + col) * 16 + h2 * 8);
            vf0n = *(const bf16x8*)(vtb + m1);
            vf1n = *(const bf16x8*)(vtb + m1 + 16);
        }

        // online softmax in exp2 domain
        float tmax = s[0];
        #pragma unroll
        for (int r = 1; r < 16; r++) tmax = fmaxf(tmax, s[r]);
        tmax = fmaxf(tmax, __shfl_xor(tmax, 32, 64));
        float mnew = fmaxf(mrun, tmax);
        float corr = exp2f(mrun - mnew);

        float ps = 0.f;
        unsigned int pw[8];
        #pragma unroll
        for (int gq = 0; gq < 4; gq++) {
            float p0 = exp2f(s[4 * gq + 0] - mnew);
            float p1 = exp2f(s[4 * gq + 1] - mnew);
            float p2 = exp2f(s[4 * gq + 2] - mnew);
            float p3 = exp2f(s[4 * gq + 3] - mnew);
            ps += (p0 + p1) + (p2 + p3);
            pw[2 * gq + 0] = f2bf(p0) | ((unsigned int)f2bf(p1) << 16);
            pw[2 * gq + 1] = f2bf(p2) | ((unsigned int)f2bf(p3) << 16);
        }
        ps += __shfl_xor(ps, 32, 64);
        lrun = lrun * corr + ps;
        mrun = mnew;
        #pragma unroll
        for (int r = 0; r < 16; r++) acc[r] *= corr;

        // P -> per-wave LDS (reg group gq covers m_local = 8gq+4h2+{0..3})
        #pragma unroll
        for (int gq = 0; gq < 4; gq++)
            *(uint2*)&p_lds[wid][col][8 * gq + 4 * h2] = make_uint2(pw[2 * gq], pw[2 * gq + 1]);

        #pragma unroll
        for (int ks = 0; ks < 2; ks++) {
            bf16x8 pf = *(bf16x8*)&p_lds[wid][col][16 * ks + 8 * h2];
            bf16x8 vf = ks ? vf1 : vf0;
            acc = __builtin_amdgcn_mfma_f32_32x32x16_bf16(vf, pf, acc, 0, 0, 0);
        }

        kf = kfn; vf0 = vf0n; vf1 = vf1n;
    }

    // merge key-splits: waves 4-7 publish, waves 0-3 combine + epilogue
    if (ksplit == 1) {
        #pragma unroll
        for (int r = 0; r < 16; r++) cmb[qsub][lane][r] = acc[r];
        cmm[qsub][lane] = mrun;
        cml[qsub][lane] = lrun;
    }
    __syncthreads();
    if (ksplit == 0) {
        float m2 = cmm[qsub][lane];
        float l2 = cml[qsub][lane];
        float M  = fmaxf(mrun, m2);
        float a1 = exp2f(mrun - M);
        float a2 = exp2f(m2 - M);
        float inv = 1.f / (lrun * a1 + l2 * a2);

        const float* pep = pe + ((size_t)(b * 256 + h * 32)) * 1024 + q0 + col;
        unsigned short* yp = y + ((size_t)(b * 256 + h * 32)) * 1024 + q0 + col;
        #pragma unroll
        for (int r = 0; r < 16; r++) {
            int c = (r & 3) + 8 * (r >> 2) + 4 * h2;
            float v = (acc[r] * a1 + cmb[qsub][lane][r] * a2) * inv + pep[(size_t)c * 1024];
            yp[(size_t)c * 1024] = f2bf(v);
        }
    }
}

// ---------------------------------------------------------------------------
extern "C" void kernel_launch(void* const* d_in, const int* in_sizes, int n_in,
                              void* d_out, int out_size, void* d_ws, size_t ws_size,
                              hipStream_t stream)
{
    const float* x      = (const float*)d_in[0];
    const float* w_qkv  = (const float*)d_in[1];
    const float* qkv_g  = (const float*)d_in[2];
    const float* qkv_b  = (const float*)d_in[3];
    const float* qkv_m  = (const float*)d_in[4];
    const float* qkv_v  = (const float*)d_in[5];
    const float* w_pe   = (const float*)d_in[6];
    const float* pe_g   = (const float*)d_in[7];
    const float* pe_b   = (const float*)d_in[8];
    const float* pe_m   = (const float*)d_in[9];
    const float* pe_v   = (const float*)d_in[10];
    const float* w_proj = (const float*)d_in[11];
    const float* proj_g = (const float*)d_in[12];
    const float* proj_b = (const float*)d_in[13];
    const float* proj_m = (const float*)d_in[14];
    const float* proj_v = (const float*)d_in[15];

    float* out = (float*)d_out;
    unsigned short* qt = (unsigned short*)d_ws;              // 2 MB
    unsigned short* kt = qt + (size_t)64 * 1024 * 16;        // 2 MB
    unsigned short* vt = kt + (size_t)64 * 1024 * 16;        // 4 MB
    float* pe = (float*)(vt + (size_t)64 * 32 * 1024);       // 8 MB
    unsigned short* y = (unsigned short*)(pe + (size_t)8 * 256 * 1024);  // 4 MB

    // 1) QKV GEMM + BN -> qt/kt (bf16 frag layout, q in exp2 domain) + vt
    gemm_mfma_kernel<512, true><<<dim3(16, 4, 8), 256, 0, stream>>>(
        x, nullptr, w_qkv, qkv_g, qkv_b, qkv_m, qkv_v, nullptr, qt, kt, vt);

    // 2) depthwise 3x3 PE conv + BN (writes pe fp32)
    pe_conv_bn_kernel<<<dim3(2048), 256, 0, stream>>>(
        vt, w_pe, pe_g, pe_b, pe_m, pe_v, pe);

    // 3) MFMA flash attention, key-split x2 (reads pe, writes y bf16)
    attn_mfma_kernel<<<dim3(8, 64), 512, 0, stream>>>(qt, kt, vt, pe, y);

    // 4) proj GEMM + BN (bf16 src) -> out
    gemm_mfma_kernel<256, false><<<dim3(16, 2, 8), 256, 0, stream>>>(
        nullptr, y, w_proj, proj_g, proj_b, proj_m, proj_v, out, nullptr, nullptr, nullptr);
}